// Round 5
// baseline (114.339 us; speedup 1.0000x reference)
//
#include <hip/hip_runtime.h>
#include <math.h>

#define C_IN  128
#define H_IN  56
#define W_IN  56
#define HW_IN (H_IN * W_IN)          // 3136
#define N_IN  8
#define O_MID 64
#define KK    5
#define NCLS  2

// ws layout (floats):
//   [0, 7680)    Weff[5][128][12]  (slot = dj*2+k; 10,11 pad)
//   [7680,7682)  beff[2]
//   [8192, ...)  xt[n][hw][c]  NHWC transpose (128B-aligned base)
#define WEFF_STRIDE 12
#define WEFF_SIZE   (5 * C_IN * WEFF_STRIDE)
#define XT_BASE     8192

// ---------------- k_weff: fold O=64 away ----------------
__global__ __launch_bounds__(256) void k_weff(const float* __restrict__ Wt,
                                              const float* __restrict__ bias,
                                              const float* __restrict__ Wlin,
                                              const float* __restrict__ blin,
                                              float* __restrict__ ws) {
    const int b = blockIdx.x;       // 0..49
    const int p = b >> 1;
    const int k = b & 1;
    const int t = threadIdx.x;
    const int c = t & 127;
    const int oh = t >> 7;
    float s = 0.f;
#pragma unroll
    for (int oo = 0; oo < 32; ++oo) {
        const int o = oh * 32 + oo;
        s += Wlin[k * O_MID + o] * Wt[(o * C_IN + c) * (KK * KK) + p];
    }
    __shared__ float part[256];
    part[t] = s;
    __syncthreads();
    if (t < 128) {
        const int di = p / KK;
        const int dj = p - di * KK;
        ws[(di * C_IN + c) * WEFF_STRIDE + dj * 2 + k] = part[c] + part[c + 128];
    }
    if (p == 0 && t < 64) {
        float v = Wlin[k * O_MID + t] * bias[t];
#pragma unroll
        for (int off = 32; off; off >>= 1) v += __shfl_down(v, off, 64);
        if (t == 0) ws[WEFF_SIZE + k] = v + blin[k];
    }
}

// ---------------- k_tr: NCHW -> NHWC ----------------
// grid (49, 2, 8), 256 thr. 64hw x 64c tile via LDS.
__global__ __launch_bounds__(256) void k_tr(const float* __restrict__ x,
                                            float* __restrict__ xt) {
    __shared__ float t[64][65];
    const int tid = threadIdx.x;
    const int hw0 = blockIdx.x * 64;
    const int c0  = blockIdx.y * 64;
    const int n   = blockIdx.z;
    const float* xp = x + (size_t)n * C_IN * HW_IN;
#pragma unroll
    for (int j = 0; j < 16; ++j) {
        const int i  = tid + 256 * j;
        const int cl = i >> 6;
        const int hl = i & 63;
        t[hl][cl] = xp[(size_t)(c0 + cl) * HW_IN + hw0 + hl];
    }
    __syncthreads();
    float* xo = xt + ((size_t)n * HW_IN + hw0) * C_IN + c0;
#pragma unroll
    for (int j = 0; j < 16; ++j) {
        const int i  = tid + 256 * j;
        const int hl = i >> 6;
        const int cl = i & 63;
        xo[(size_t)hl * C_IN + cl] = t[hl][cl];
    }
}

// ---------------- k_part: 4x8 tile, all 25 p, NHWC input ----------------
// grid (7 tx, 14 ty, 8 n), 320 thr = 5 waves (wave = di).
// Lane: strip = lane&7 (sy=strip>>1, sx0=(strip&1)*4), cq = lane>>3.
// Chunk = 32 channels, 4 chunks, dbuf. Compute c_l = 4*cq + i (i 0..3).
#define PAD_X   100                       // [c][96 payload + 4 pad]
#define XCHUNK  (32 * PAD_X)              // 3200 fl
#define WCHUNK  (5 * 32 * WEFF_STRIDE)    // 1920 fl

__global__ __launch_bounds__(320) void k_part(const float* __restrict__ ws,
                                              float* __restrict__ out) {
    __shared__ float xs[2][XCHUNK];       // 25600 B
    __shared__ float wb[2][WCHUNK];       // 15360 B  -> total 40960 B
    float* red = &xs[0][0];               // aliased: 1280 fl

    const int tid   = threadIdx.x;
    const int w     = tid >> 6;           // di
    const int lane  = tid & 63;
    const int strip = lane & 7;
    const int cq    = lane >> 3;
    const int sy    = strip >> 1;
    const int sx0   = (strip & 1) << 2;
    const int x0    = blockIdx.x * 8;
    const int y0    = blockIdx.y * 4;
    const int n     = blockIdx.z;

    const float* xt = ws + XT_BASE + (size_t)n * HW_IN * C_IN;
    const float b0 = ws[WEFF_SIZE + 0];
    const float b1 = ws[WEFF_SIZE + 1];

    // x staging map: 3 rounds x (8 c-quads x 8 pos) per wave-set of 256... 320 thr:
    // i = r*1024 + tid*4 would overrun; use (tid&7)=c-quad, (tid>>3)=pos-within-round.
    // 320 threads: pos = (tid>>3) in 0..39, need 0..31 per round -> threads with
    // (tid>>3) >= 32 idle per round; rounds r: pos_r = (tid>>3) + 32*r? That wastes.
    // Instead: linear i over 3072 float-quads? payload = 96 pos * 32 c = 768 quads.
    // 768 quads / 320 thr = 3 rounds (some idle). quad q = tid + 320*r, q<768:
    //   c4 = (q & 7)*4, pos = q >> 3  (0..95), row = pos/12, col = pos%12.
    int goff[3], lpos[3], lc4[3];
#pragma unroll
    for (int r = 0; r < 3; ++r) {
        const int q = tid + 320 * r;
        if (q < 768) {
            const int c4  = (q & 7) << 2;
            const int pos = q >> 3;
            const int row = pos / 12;
            const int col = pos - row * 12;
            const int gy  = y0 + row - 2;
            const int gx  = x0 + col - 2;
            lc4[r]  = c4;
            lpos[r] = pos;
            goff[r] = ((unsigned)gy < H_IN && (unsigned)gx < W_IN)
                          ? ((gy * W_IN + gx) * C_IN + c4) : -1;
        } else { goff[r] = -2; lpos[r] = 0; lc4[r] = 0; }
    }
    // W staging map: 1920 fl = 320*(float4 + float2)
    const int i4  = tid * 4;              // 0..1279
    const int di4 = i4 / 384;
    const int gw4 = di4 * (C_IN * WEFF_STRIDE) + (i4 - di4 * 384);
    const int i2  = 1280 + tid * 2;       // 1280..1918
    const int di2 = i2 / 384;
    const int gw2 = di2 * (C_IN * WEFF_STRIDE) + (i2 - di2 * 384);

    // stage chunk 0
    {
#pragma unroll
        for (int r = 0; r < 3; ++r) {
            if (goff[r] == -2) continue;
            float4 v = make_float4(0.f, 0.f, 0.f, 0.f);
            if (goff[r] >= 0) v = *(const float4*)&xt[goff[r]];
            float* d = &xs[0][lc4[r] * PAD_X + lpos[r]];
            d[0] = v.x; d[PAD_X] = v.y; d[2 * PAD_X] = v.z; d[3 * PAD_X] = v.w;
        }
        *(float4*)&wb[0][i4] = *(const float4*)&ws[gw4];
        *(float2*)&wb[0][i2] = *(const float2*)&ws[gw2];
    }
    __syncthreads();

    float acc[5][2][4];                   // [dj][k][j]
#pragma unroll
    for (int a = 0; a < 5; ++a)
#pragma unroll
        for (int b = 0; b < 2; ++b)
#pragma unroll
            for (int j = 0; j < 4; ++j) acc[a][b][j] = 0.f;

    const int rbase = (sy + w) * 12 + sx0;

    for (int cc = 0; cc < 4; ++cc) {
        const float* cur  = xs[cc & 1];
        const float* curW = wb[cc & 1];
        float4 pfx[3]; float4 pw4; float2 pw2;
        if (cc < 3) {
            const int c0n = (cc + 1) * 32;
#pragma unroll
            for (int r = 0; r < 3; ++r) {
                pfx[r] = make_float4(0.f, 0.f, 0.f, 0.f);
                if (goff[r] >= 0) pfx[r] = *(const float4*)&xt[goff[r] + c0n];
            }
            pw4 = *(const float4*)&ws[gw4 + (cc + 1) * 384];
            pw2 = *(const float2*)&ws[gw2 + (cc + 1) * 384];
        }
#pragma unroll
        for (int i = 0; i < 4; ++i) {
            const int c_l = (cq << 2) + i;
            const float4 xa = *(const float4*)&cur[c_l * PAD_X + rbase];
            const float4 xb = *(const float4*)&cur[c_l * PAD_X + rbase + 4];
            const float xr[8] = {xa.x, xa.y, xa.z, xa.w, xb.x, xb.y, xb.z, xb.w};
            const float* wp = &curW[w * 384 + c_l * WEFF_STRIDE];
            const float4 wa = *(const float4*)(wp);
            const float4 wbv = *(const float4*)(wp + 4);
            const float2 wc = *(const float2*)(wp + 8);
            const float wv[10] = {wa.x, wa.y, wa.z, wa.w,
                                  wbv.x, wbv.y, wbv.z, wbv.w, wc.x, wc.y};
#pragma unroll
            for (int dj = 0; dj < 5; ++dj)
#pragma unroll
                for (int j = 0; j < 4; ++j) {
                    const float xv = xr[dj + j];
                    acc[dj][0][j] = fmaf(xv, wv[dj * 2 + 0], acc[dj][0][j]);
                    acc[dj][1][j] = fmaf(xv, wv[dj * 2 + 1], acc[dj][1][j]);
                }
        }
        if (cc < 3) {
            float* nxt  = xs[(cc & 1) ^ 1];
            float* nxtW = wb[(cc & 1) ^ 1];
#pragma unroll
            for (int r = 0; r < 3; ++r) {
                if (goff[r] == -2) continue;
                float* d = &nxt[lc4[r] * PAD_X + lpos[r]];
                d[0] = pfx[r].x; d[PAD_X] = pfx[r].y;
                d[2 * PAD_X] = pfx[r].z; d[3 * PAD_X] = pfx[r].w;
            }
            *(float4*)&nxtW[i4] = pw4;
            *(float2*)&nxtW[i2] = pw2;
        }
        __syncthreads();
    }

    // reduce over cq (lane bits 3,4,5)
#pragma unroll
    for (int a = 0; a < 5; ++a)
#pragma unroll
        for (int b = 0; b < 2; ++b)
#pragma unroll
            for (int j = 0; j < 4; ++j) {
                float v = acc[a][b][j];
                v += __shfl_xor(v, 8, 64);
                v += __shfl_xor(v, 16, 64);
                v += __shfl_xor(v, 32, 64);
                acc[a][b][j] = v;
            }

    // per-di stats -> red[di][strip][j][k][4]
    if (cq == 0) {
#pragma unroll
        for (int j = 0; j < 4; ++j)
#pragma unroll
            for (int k = 0; k < 2; ++k) {
                const float be = k ? b1 : b0;
                float A = 0.f, X = 0.f, Cs = 0.f;
#pragma unroll
                for (int dj = 0; dj < 5; ++dj) {
                    const float v  = acc[dj][k][j] + be;
                    const float av = fabsf(v);
                    A  += av;
                    X  += av * (float)(dj - 2);
                    Cs += v;
                }
                float* rp = &red[(((w * 8 + strip) * 4 + j) * 2 + k) * 4];
                rp[0] = A; rp[1] = X; rp[2] = Cs; rp[3] = A * (float)(w - 2);
            }
    }
    __syncthreads();

    if (tid < 64) {
        const int strip = tid >> 3;
        const int j     = (tid >> 1) & 3;
        const int k     = tid & 1;
        float A = 0.f, X = 0.f, Cs = 0.f, Y = 0.f;
#pragma unroll
        for (int d = 0; d < 5; ++d) {
            const float* rp = &red[(((d * 8 + strip) * 4 + j) * 2 + k) * 4];
            A += rp[0]; X += rp[1]; Cs += rp[2]; Y += rp[3];
        }
        const float xd = X / A;
        const float yd = Y / A;
        const float drift = sqrtf(xd * xd + yd * yd);
        const float o = Cs * expf(-0.5f * drift);
        const int gy = y0 + (strip >> 1);
        const int gx = x0 + ((strip & 1) << 2) + j;
        out[((size_t)(n * H_IN + gy) * W_IN + gx) * NCLS + k] = o;
    }
}

extern "C" void kernel_launch(void* const* d_in, const int* in_sizes, int n_in,
                              void* d_out, int out_size, void* d_ws, size_t ws_size,
                              hipStream_t stream) {
    const float* x    = (const float*)d_in[0];
    const float* Wt   = (const float*)d_in[1];
    const float* bias = (const float*)d_in[2];
    const float* Wlin = (const float*)d_in[3];
    const float* blin = (const float*)d_in[4];
    float* ws = (float*)d_ws;

    k_weff<<<dim3(KK * KK * NCLS), dim3(256), 0, stream>>>(Wt, bias, Wlin, blin, ws);
    k_tr<<<dim3(49, 2, N_IN), dim3(256), 0, stream>>>(x, ws + XT_BASE);
    k_part<<<dim3(7, 14, N_IN), dim3(320), 0, stream>>>(ws, (float*)d_out);
}

// Round 6
// 90.081 us; speedup vs baseline: 1.2693x; 1.2693x over previous
//
#include <hip/hip_runtime.h>
#include <math.h>

#define C_IN  128
#define H_IN  56
#define W_IN  56
#define HW_IN (H_IN * W_IN)          // 3136
#define N_IN  8
#define O_MID 64
#define KK    5
#define NCLS  2

// ws layout (floats):
//   [0, 7680)    Weff[5][128][12]  (slot = dj*2+k; 10,11 pad)
//   [7680,7682)  beff[2]
//   [8192, ...)  G[p][n][hw][k]  p=di*5+dj, float2 per (hw): 25*8*3136*2 = 1,254,400 fl
#define WEFF_STRIDE 12
#define WEFF_SIZE   (5 * C_IN * WEFF_STRIDE)
#define G_BASE      8192

// ---------------- k_weff: fold O=64 away ----------------
__global__ __launch_bounds__(256) void k_weff(const float* __restrict__ Wt,
                                              const float* __restrict__ bias,
                                              const float* __restrict__ Wlin,
                                              const float* __restrict__ blin,
                                              float* __restrict__ ws) {
    const int b = blockIdx.x;       // 0..49
    const int p = b >> 1;
    const int k = b & 1;
    const int t = threadIdx.x;
    const int c = t & 127;
    const int oh = t >> 7;
    float s = 0.f;
#pragma unroll
    for (int oo = 0; oo < 32; ++oo) {
        const int o = oh * 32 + oo;
        s += Wlin[k * O_MID + o] * Wt[(o * C_IN + c) * (KK * KK) + p];
    }
    __shared__ float part[256];
    part[t] = s;
    __syncthreads();
    if (t < 128) {
        const int di = p / KK;
        const int dj = p - di * KK;
        ws[(di * C_IN + c) * WEFF_STRIDE + dj * 2 + k] = part[c] + part[c + 128];
    }
    if (p == 0 && t < 64) {
        float v = Wlin[k * O_MID + t] * bias[t];
#pragma unroll
        for (int off = 32; off; off >>= 1) v += __shfl_down(v, off, 64);
        if (t == 0) ws[WEFF_SIZE + k] = v + blin[k];
    }
}

// ---------------- k_gemm: G[p][n][hw][k] = sum_c x[n][c][hw] * Weff[di][c][dj*2+k] ----------------
// grid (49 hw-chunks, 5 di, 8 n), 64 threads (1 wave). lane = hw within chunk.
// x reads: lane-contiguous 256B. W reads: wave-uniform -> scalar cache.
__global__ __launch_bounds__(64) void k_gemm(const float* __restrict__ x,
                                             const float* __restrict__ ws,
                                             float* __restrict__ g) {
    const int lane = threadIdx.x;
    const int hw   = blockIdx.x * 64 + lane;
    const int di   = blockIdx.y;
    const int n    = blockIdx.z;

    const float* xc = x + (size_t)n * (C_IN * HW_IN) + hw;
    const float* wd = ws + di * (C_IN * WEFF_STRIDE);

    float acc[5][2];
#pragma unroll
    for (int dj = 0; dj < 5; ++dj) { acc[dj][0] = 0.f; acc[dj][1] = 0.f; }

#pragma unroll 8
    for (int c = 0; c < C_IN; ++c) {
        const float xv = xc[(size_t)c * HW_IN];
        const float* wr = wd + c * WEFF_STRIDE;
#pragma unroll
        for (int dj = 0; dj < 5; ++dj) {
            acc[dj][0] = fmaf(xv, wr[dj * 2 + 0], acc[dj][0]);
            acc[dj][1] = fmaf(xv, wr[dj * 2 + 1], acc[dj][1]);
        }
    }

#pragma unroll
    for (int dj = 0; dj < 5; ++dj) {
        const int p = di * 5 + dj;
        float2 v = make_float2(acc[dj][0], acc[dj][1]);
        *(float2*)&g[(((size_t)p * N_IN + n) * HW_IN + hw) * 2] = v;
    }
}

// ---------------- k_final: gather shifted G, abs-stats, output ----------------
// grid (49, 8), 64 threads. lane = out pixel within chunk.
__global__ __launch_bounds__(64) void k_final(const float* __restrict__ ws,
                                              const float* __restrict__ g,
                                              float* __restrict__ out) {
    const int lane = threadIdx.x;
    const int hw   = blockIdx.x * 64 + lane;
    const int n    = blockIdx.y;
    const int y    = hw / W_IN;
    const int x    = hw - y * W_IN;

    const float be0 = ws[WEFF_SIZE + 0];
    const float be1 = ws[WEFF_SIZE + 1];

    float A0 = 0.f, X0 = 0.f, Y0 = 0.f, C0 = 0.f;
    float A1 = 0.f, X1 = 0.f, Y1 = 0.f, C1 = 0.f;

#pragma unroll
    for (int di = 0; di < 5; ++di) {
        const int yy = y + di - 2;
        const bool rowok = (unsigned)yy < H_IN;
#pragma unroll
        for (int dj = 0; dj < 5; ++dj) {
            const int xx = x + dj - 2;
            const bool ok = rowok && ((unsigned)xx < W_IN);
            float2 gv = make_float2(0.f, 0.f);
            if (ok) {
                const int p = di * 5 + dj;
                gv = *(const float2*)&g[(((size_t)p * N_IN + n) * HW_IN + yy * W_IN + xx) * 2];
            }
            const float v0 = gv.x + be0;
            const float v1 = gv.y + be1;
            const float a0 = fabsf(v0);
            const float a1 = fabsf(v1);
            const float fdj = (float)(dj - 2);
            const float fdi = (float)(di - 2);
            A0 += a0; X0 = fmaf(a0, fdj, X0); Y0 = fmaf(a0, fdi, Y0); C0 += v0;
            A1 += a1; X1 = fmaf(a1, fdj, X1); Y1 = fmaf(a1, fdi, Y1); C1 += v1;
        }
    }

    const float xd0 = X0 / A0, yd0 = Y0 / A0;
    const float xd1 = X1 / A1, yd1 = Y1 / A1;
    const float o0 = C0 * expf(-0.5f * sqrtf(xd0 * xd0 + yd0 * yd0));
    const float o1 = C1 * expf(-0.5f * sqrtf(xd1 * xd1 + yd1 * yd1));
    *(float2*)&out[((size_t)n * HW_IN + hw) * 2] = make_float2(o0, o1);
}

extern "C" void kernel_launch(void* const* d_in, const int* in_sizes, int n_in,
                              void* d_out, int out_size, void* d_ws, size_t ws_size,
                              hipStream_t stream) {
    const float* x    = (const float*)d_in[0];
    const float* Wt   = (const float*)d_in[1];
    const float* bias = (const float*)d_in[2];
    const float* Wlin = (const float*)d_in[3];
    const float* blin = (const float*)d_in[4];
    float* ws = (float*)d_ws;

    k_weff<<<dim3(KK * KK * NCLS), dim3(256), 0, stream>>>(Wt, bias, Wlin, blin, ws);
    k_gemm<<<dim3(49, KK, N_IN), dim3(64), 0, stream>>>(x, ws, ws + G_BASE);
    k_final<<<dim3(49, N_IN), dim3(64), 0, stream>>>(ws, ws + G_BASE, (float*)d_out);
}